// Round 16
// baseline (8064.927 us; speedup 1.0000x reference)
//
#include <hip/hip_runtime.h>

#define DT 0.5f

constexpr int NB   = 256;
constexpr int S0N  = 10;
constexpr int S1SZ = 2048;   // 128*4*4
constexpr int S2SZ = 9216;   // 64*12*12
constexpr int O_S0 = 0;
constexpr int O_S1 = NB * S0N;            // 2560
constexpr int O_S2 = O_S1 + NB * S1SZ;    // 526848
constexpr int STATE_TOTAL = O_S2 + NB * S2SZ; // 2886144
constexpr int T_RUN = 10;                 // sync T=10 (confirmed)

// ARITHMETIC HYPOTHESIS: np ref = vanilla numpy fp32 port.
//  - convs: einsum/loops -> NON-FMA (mul round, add round), C-order (ci,kh,kw)
//  - fc / td1: literal '@' -> BLAS sgemm, k-sequential FMA
//  - state fp32; elementwise updates exact-matched.
// My prior runs tested seq-FMA-fp32 (r1) and fp64 (r5) only — both ≠ np.

__device__ __forceinline__ float rho(float x) { return fminf(fmaxf(x, 0.f), 1.f); }
// non-FMA accumulate: two roundings, contraction-proof
__device__ __forceinline__ float nacc(float a, float b, float s) {
    return __fadd_rn(s, __fmul_rn(a, b));
}

__global__ void k_sentinel(float* out) { out[0] = 3.0e38f; }

// ---------------- one-time: conv(data,Wc1)+bc1 -> 2x2 maxpool -> p1 (non-FMA) ----------------
__global__ void k_p1(const float* __restrict__ data, const float* __restrict__ Wc1,
                     const float* __restrict__ bc1, float* __restrict__ p1) {
    int idx = blockIdx.x * 256 + threadIdx.x;      // over NB*64*144
    int wo = idx % 12; int t = idx / 12;
    int ho = t % 12;   t /= 12;
    int c = t & 63;    int b = t >> 6;
    const float* dp = data + b * 784;
    const float* w = Wc1 + c * 25;
    float bias = bc1[c];                           // == 0 in this problem
    float best = -3.4e38f;
#pragma unroll
    for (int dy = 0; dy < 2; dy++)
#pragma unroll
    for (int dx = 0; dx < 2; dx++) {
        int oy = 2 * ho + dy, ox = 2 * wo + dx;
        float s = 0.f;
#pragma unroll
        for (int kh = 0; kh < 5; kh++)
#pragma unroll
        for (int kw = 0; kw < 5; kw++)
            s = nacc(dp[(oy + kh) * 28 + (ox + kw)], w[kh * 5 + kw], s);
        s = __fadd_rn(s, bias);                    // bias added after (numpy style)
        best = fmaxf(best, s);
    }
    p1[idx] = best;
}

// ---------------- one-time: Wt[ci][co][a][b] = Wc0[co][ci][4-a][4-b] ----------------
__global__ void k_wt(const float* __restrict__ Wc0, float* __restrict__ Wt) {
    int i = blockIdx.x * 256 + threadIdx.x;        // over 204800
    int bb = i % 5; int t = i / 5;
    int a  = t % 5; t /= 5;
    int co = t & 127; int ci = t >> 7;
    Wt[i] = Wc0[(co * 64 + ci) * 25 + (4 - a) * 5 + (4 - bb)];
}

// ------- per step: a0 = rho(s1 @ Wfc^T + bfc); s0 update. One thread per (b,j), k-seq FMA -------
__global__ __launch_bounds__(256) void k_fc(const float* __restrict__ s_old,
                                            const float* __restrict__ Wfc,
                                            const float* __restrict__ bfc,
                                            float* __restrict__ s_new) {
    int i = blockIdx.x * 256 + threadIdx.x;        // over NB*S0N = 2560
    if (i >= NB * S0N) return;
    int b = i / S0N, j = i % S0N;
    const float* s1 = s_old + O_S1 + b * S1SZ;
    const float* w  = Wfc + j * S1SZ;
    float sum = 0.f;
    for (int k = 0; k < S1SZ; k++) sum = fmaf(s1[k], w[k], sum);   // BLAS k-seq FMA
    float a0 = rho(__fadd_rn(sum, bfc[j]));
    float s0 = s_old[O_S0 + i];
    s_new[O_S0 + i] = s0 + DT * (a0 - s0);
}

// ------- per step: conv(s2,Wc0) (non-FMA) -> pool/argmax -> +td1 -> s1 update -------
__global__ __launch_bounds__(256) void k_conv0(const float* __restrict__ s_old,
                                               const float* __restrict__ Wc0,
                                               const float* __restrict__ bc0,
                                               const float* __restrict__ Wfc,
                                               float* __restrict__ s_new,
                                               int* __restrict__ i0) {
    __shared__ float lds[S2SZ];                    // 36.9 KB: full s2 plane
    int b   = blockIdx.x >> 3;
    int cog = blockIdx.x & 7;
    const float* s2 = s_old + O_S2 + b * S2SZ;
    for (int i = threadIdx.x; i < S2SZ; i += 256) lds[i] = s2[i];
    __syncthreads();

    int co = cog * 16 + (threadIdx.x >> 4);
    int sp = threadIdx.x & 15;
    int py = sp >> 2, px = sp & 3;
    const float* wb = Wc0 + co * 1600;
    float bias = bc0[co];                          // == 0
    float acc[4];
#pragma unroll
    for (int p = 0; p < 4; p++) {                  // p = dy*2 + dx
        int oy = 2 * py + (p >> 1), ox = 2 * px + (p & 1);
        float s = 0.f;
        for (int ci = 0; ci < 64; ci++) {          // einsum C-order (c, kh, kw)
            const float* l = lds + ci * 144 + oy * 12 + ox;
            const float* w = wb + ci * 25;
#pragma unroll
            for (int kh = 0; kh < 5; kh++)
#pragma unroll
            for (int kw = 0; kw < 5; kw++)
                s = nacc(l[kh * 12 + kw], w[kh * 5 + kw], s);
        }
        acc[p] = __fadd_rn(s, bias);
    }
    // first-max argmax (np.argmax)
    float m = acc[0]; int idx = 0;
#pragma unroll
    for (int k = 1; k < 4; k++) if (acc[k] > m) { m = acc[k]; idx = k; }

    int f = co * 16 + sp;
    const float* s0p = s_old + O_S0 + b * S0N;
    float td1 = 0.f;
#pragma unroll
    for (int j = 0; j < 10; j++) td1 = fmaf(s0p[j], Wfc[j * 2048 + f], td1);  // BLAS k=10
    float s1o = s_old[O_S1 + b * S1SZ + f];
    s_new[O_S1 + b * S1SZ + f] = s1o + DT * (rho(__fadd_rn(m, td1)) - s1o);
    i0[b * S1SZ + f] = idx;
}

// ------- per step: unpool -> conv_transpose (non-FMA) -> +p1 -> s2 update -------
__global__ __launch_bounds__(256) void k_tconv(const float* __restrict__ s_old,
                                               const float* __restrict__ Wt,
                                               const float* __restrict__ p1,
                                               const int* __restrict__ i0,
                                               float* __restrict__ s_new) {
    __shared__ float up[128 * 64];                 // 32 KB: all unpool planes
    int b = blockIdx.x / 9;
    int g = blockIdx.x % 9;
    const float* s1p = s_old + O_S1 + b * S1SZ;
    const int*   i0p = i0 + b * S1SZ;
    for (int i = threadIdx.x; i < 8192; i += 256) {
        int co = i >> 6, u = (i >> 3) & 7, v = i & 7;
        int f = co * 16 + (u >> 1) * 4 + (v >> 1);
        up[i] = (i0p[f] == ((u & 1) * 2 + (v & 1))) ? s1p[f] : 0.f;
    }
    __syncthreads();

    int ci = threadIdx.x >> 2;                     // 0..63 output chan
    int stile = g * 4 + (threadIdx.x & 3);         // 0..35
    int sr = stile / 6, sc = stile % 6;
    int y0 = sr * 2, x0 = sc * 2;
    float a00 = 0.f, a01 = 0.f, a10 = 0.f, a11 = 0.f;
    const float* wci = Wt + ci * 3200;

    for (int co = 0; co < 128; co++) {             // einsum C-order (c, kh, kw)
        float win[36];
#pragma unroll
        for (int r = 0; r < 6; r++) {
            int u = y0 - 4 + r;
            bool okr = ((unsigned)u < 8u);
#pragma unroll
            for (int c = 0; c < 6; c++) {
                int v = x0 - 4 + c;
                float val = up[co * 64 + (u & 7) * 8 + (v & 7)];
                win[r * 6 + c] = (okr && (unsigned)v < 8u) ? val : 0.f;
            }
        }
        const float* w = wci + co * 25;
#pragma unroll
        for (int kh = 0; kh < 5; kh++)
#pragma unroll
        for (int kw = 0; kw < 5; kw++) {
            float wv = w[kh * 5 + kw];
            a00 = nacc(win[kh * 6 + kw],           wv, a00);
            a01 = nacc(win[kh * 6 + kw + 1],       wv, a01);
            a10 = nacc(win[(kh + 1) * 6 + kw],     wv, a10);
            a11 = nacc(win[(kh + 1) * 6 + kw + 1], wv, a11);
        }
    }
    int pbase = b * S2SZ + ci * 144;
    float acc[4] = {a00, a01, a10, a11};
#pragma unroll
    for (int dy = 0; dy < 2; dy++)
#pragma unroll
    for (int dx = 0; dx < 2; dx++) {
        int o = pbase + (y0 + dy) * 12 + (x0 + dx);
        float s2o = s_old[O_S2 + o];
        s_new[O_S2 + o] = s2o + DT * (rho(__fadd_rn(p1[o], acc[dy * 2 + dx])) - s2o);
    }
}

extern "C" void kernel_launch(void* const* d_in, const int* in_sizes, int n_in,
                              void* d_out, int out_size, void* d_ws, size_t ws_size,
                              hipStream_t stream) {
    const float* data  = (const float*)d_in[0];
    const float* s0_in = (const float*)d_in[1];
    const float* s1_in = (const float*)d_in[2];
    const float* s2_in = (const float*)d_in[3];
    const float* Wfc   = (const float*)d_in[4];
    const float* bfc   = (const float*)d_in[5];
    const float* Wc0   = (const float*)d_in[6];
    const float* bc0   = (const float*)d_in[7];
    const float* Wc1   = (const float*)d_in[8];
    const float* bc1   = (const float*)d_in[9];
    float* out = (float*)d_out;

    float* wsf = (float*)d_ws;
    float* X   = wsf;                          // ping-pong partner of d_out
    float* p1  = X + STATE_TOTAL;              // NB*S2SZ
    float* Wt  = p1 + NB * S2SZ;               // 204800
    int*   i0  = (int*)(Wt + 204800);          // NB*S1SZ

    size_t needed = (size_t)(STATE_TOTAL + NB * S2SZ + 204800 + NB * S1SZ) * 4;
    if (ws_size < needed) { k_sentinel<<<1, 1, 0, stream>>>(out); return; }

    // state t=0 -> d_out; 10 steps out->X->out... end in out
    hipMemcpyAsync(out + O_S0, s0_in, NB * S0N * sizeof(float), hipMemcpyDeviceToDevice, stream);
    hipMemcpyAsync(out + O_S1, s1_in, NB * S1SZ * sizeof(float), hipMemcpyDeviceToDevice, stream);
    hipMemcpyAsync(out + O_S2, s2_in, NB * S2SZ * sizeof(float), hipMemcpyDeviceToDevice, stream);

    k_p1<<<NB * 64 * 144 / 256, 256, 0, stream>>>(data, Wc1, bc1, p1);
    k_wt<<<204800 / 256, 256, 0, stream>>>(Wc0, Wt);

    for (int t = 0; t < T_RUN; t++) {
        const float* src = (t & 1) ? X : out;
        float*       dst = (t & 1) ? out : X;
        k_fc   <<<10,     256, 0, stream>>>(src, Wfc, bfc, dst);
        k_conv0<<<NB * 8, 256, 0, stream>>>(src, Wc0, bc0, Wfc, dst, i0);
        k_tconv<<<NB * 9, 256, 0, stream>>>(src, Wt, p1, i0, dst);
    }
}

// Round 17
// 5443.307 us; speedup vs baseline: 1.4816x; 1.4816x over previous
//
#include <hip/hip_runtime.h>

#define DT 0.5f

constexpr int NB   = 256;
constexpr int S0N  = 10;
constexpr int S1SZ = 2048;   // 128*4*4
constexpr int S2SZ = 9216;   // 64*12*12
constexpr int O_S0 = 0;
constexpr int O_S1 = NB * S0N;            // 2560
constexpr int O_S2 = O_S1 + NB * S1SZ;    // 526848
constexpr int STATE_TOTAL = O_S2 + NB * S2SZ; // 2886144
constexpr int T_RUN = 10;

// GOLDEN ARITHMETIC (r16, passed): non-FMA (mul-round, add-round) convs in
// (ci,kh,kw) C-order; k-seq FMA for '@'. This round restructures ONLY data
// movement — every reduction keeps the identical scalar op sequence.

__device__ __forceinline__ float rho(float x) { return fminf(fmaxf(x, 0.f), 1.f); }
__device__ __forceinline__ float nacc(float a, float b, float s) {
    return __fadd_rn(s, __fmul_rn(a, b));
}

__global__ void k_sentinel(float* out) { out[0] = 3.0e38f; }

// ---------------- one-time: conv(data,Wc1)+bc1 -> 2x2 maxpool -> p1 ----------------
__global__ void k_p1(const float* __restrict__ data, const float* __restrict__ Wc1,
                     const float* __restrict__ bc1, float* __restrict__ p1) {
    int idx = blockIdx.x * 256 + threadIdx.x;      // over NB*64*144
    int wo = idx % 12; int t = idx / 12;
    int ho = t % 12;   t /= 12;
    int c = t & 63;    int b = t >> 6;
    const float* dp = data + b * 784;
    const float* w = Wc1 + c * 25;
    float bias = bc1[c];
    float best = -3.4e38f;
#pragma unroll
    for (int dy = 0; dy < 2; dy++)
#pragma unroll
    for (int dx = 0; dx < 2; dx++) {
        int oy = 2 * ho + dy, ox = 2 * wo + dx;
        float s = 0.f;
#pragma unroll
        for (int kh = 0; kh < 5; kh++)
#pragma unroll
        for (int kw = 0; kw < 5; kw++)
            s = nacc(dp[(oy + kh) * 28 + (ox + kw)], w[kh * 5 + kw], s);
        s = __fadd_rn(s, bias);
        best = fmaxf(best, s);
    }
    p1[idx] = best;
}

// ---------------- one-time: Wt[ci][co][a][b] = Wc0[co][ci][4-a][4-b] ----------------
__global__ void k_wt(const float* __restrict__ Wc0, float* __restrict__ Wt) {
    int i = blockIdx.x * 256 + threadIdx.x;        // over 204800
    int bb = i % 5; int t = i / 5;
    int a  = t % 5; t /= 5;
    int co = t & 127; int ci = t >> 7;
    Wt[i] = Wc0[(co * 64 + ci) * 25 + (4 - a) * 5 + (4 - bb)];
}

// ------- per step: a0 = rho(s1 @ Wfc^T + bfc); s0 update. Chain identical to r16 -------
__global__ __launch_bounds__(64) void k_fc(const float* __restrict__ s_old,
                                           const float* __restrict__ Wfc,
                                           const float* __restrict__ bfc,
                                           float* __restrict__ s_new) {
    int i = blockIdx.x * 64 + threadIdx.x;         // 40 blocks x 64 = 2560 exactly
    int b = i / S0N, j = i % S0N;
    const float4* s1 = (const float4*)(s_old + O_S1 + b * S1SZ);
    const float4* w  = (const float4*)(Wfc + j * S1SZ);
    float sum = 0.f;
#pragma unroll 4
    for (int k = 0; k < S1SZ / 4; k++) {           // k-sequential FMA chain (BLAS)
        float4 a = s1[k], c = w[k];
        sum = fmaf(a.x, c.x, sum);
        sum = fmaf(a.y, c.y, sum);
        sum = fmaf(a.z, c.z, sum);
        sum = fmaf(a.w, c.w, sum);
    }
    float a0 = rho(__fadd_rn(sum, bfc[j]));
    float s0 = s_old[O_S0 + i];
    s_new[O_S0 + i] = s0 + DT * (a0 - s0);
}

// ------- per step: conv(s2,Wc0) -> pool/argmax -> +td1 -> s1 update -------
// window-in-registers; arithmetic order (ci,kh,kw) per accumulator == r16
__global__ __launch_bounds__(256) void k_conv0(const float* __restrict__ s_old,
                                               const float* __restrict__ Wc0,
                                               const float* __restrict__ bc0,
                                               const float* __restrict__ Wfc,
                                               float* __restrict__ s_new,
                                               int* __restrict__ i0) {
    __shared__ float lds[S2SZ];                    // 36.9 KB: full s2 plane
    int b   = blockIdx.x >> 3;
    int cog = blockIdx.x & 7;
    const float4* s2v = (const float4*)(s_old + O_S2 + b * S2SZ);
    float4* ldsv = (float4*)lds;
    for (int i = threadIdx.x; i < S2SZ / 4; i += 256) ldsv[i] = s2v[i];
    __syncthreads();

    int co = cog * 16 + (threadIdx.x >> 4);
    int sp = threadIdx.x & 15;
    int py = sp >> 2, px = sp & 3;
    const float* wb = Wc0 + co * 1600;
    float bias = bc0[co];
    float a00 = 0.f, a01 = 0.f, a10 = 0.f, a11 = 0.f;
    const float* base = lds + (2 * py) * 12 + 2 * px;

    for (int ci = 0; ci < 64; ci++) {
        float win[36];                             // 6x6 window, wide LDS reads
        const float* bp = base + ci * 144;
#pragma unroll
        for (int r = 0; r < 6; r++) {
            const float2* rp = (const float2*)(bp + r * 12);  // even-aligned
            float2 v0 = rp[0], v1 = rp[1], v2 = rp[2];
            win[r * 6 + 0] = v0.x; win[r * 6 + 1] = v0.y;
            win[r * 6 + 2] = v1.x; win[r * 6 + 3] = v1.y;
            win[r * 6 + 4] = v2.x; win[r * 6 + 5] = v2.y;
        }
        const float* wr = wb + ci * 25;
#pragma unroll
        for (int kh = 0; kh < 5; kh++)
#pragma unroll
        for (int kw = 0; kw < 5; kw++) {
            float wv = wr[kh * 5 + kw];
            a00 = nacc(win[kh * 6 + kw],           wv, a00);
            a01 = nacc(win[kh * 6 + kw + 1],       wv, a01);
            a10 = nacc(win[(kh + 1) * 6 + kw],     wv, a10);
            a11 = nacc(win[(kh + 1) * 6 + kw + 1], wv, a11);
        }
    }
    float acc[4] = {__fadd_rn(a00, bias), __fadd_rn(a01, bias),
                    __fadd_rn(a10, bias), __fadd_rn(a11, bias)};
    // first-max argmax (np.argmax)
    float m = acc[0]; int idx = 0;
#pragma unroll
    for (int k = 1; k < 4; k++) if (acc[k] > m) { m = acc[k]; idx = k; }

    int f = co * 16 + sp;
    const float* s0p = s_old + O_S0 + b * S0N;
    float td1 = 0.f;
#pragma unroll
    for (int j = 0; j < 10; j++) td1 = fmaf(s0p[j], Wfc[j * 2048 + f], td1);
    float s1o = s_old[O_S1 + b * S1SZ + f];
    s_new[O_S1 + b * S1SZ + f] = s1o + DT * (rho(__fadd_rn(m, td1)) - s1o);
    i0[b * S1SZ + f] = idx;
}

// ------- per step: unpool -> conv_transpose -> +p1 -> s2 update -------
// zero-padded [32co][16][16] LDS planes (4 chunks); order (co asc, kh, kw) == r16
__global__ __launch_bounds__(256) void k_tconv(const float* __restrict__ s_old,
                                               const float* __restrict__ Wt,
                                               const float* __restrict__ p1,
                                               const int* __restrict__ i0,
                                               float* __restrict__ s_new) {
    __shared__ float pad[32 * 256];                // 32 KB: 32 co x 16x16 padded
    int b = blockIdx.x / 9;
    int g = blockIdx.x % 9;
    const float* s1p = s_old + O_S1 + b * S1SZ;
    const int*   i0p = i0 + b * S1SZ;

    int ci = threadIdx.x >> 2;                     // 0..63 output chan
    int stile = g * 4 + (threadIdx.x & 3);         // 0..35
    int sr = stile / 6, sc = stile % 6;
    int y0 = sr * 2, x0 = sc * 2;
    float a00 = 0.f, a01 = 0.f, a10 = 0.f, a11 = 0.f;

    for (int chunk = 0; chunk < 4; chunk++) {      // fwd-out chans in 32-blocks, asc
        __syncthreads();
        for (int i = threadIdx.x; i < 8192; i += 256) {
            int co_l = i >> 8;                     // 0..31
            int ro = (i >> 4) & 15, cl = i & 15;
            int u = ro - 4, v = cl - 4;
            float val = 0.f;
            if ((unsigned)u < 8u && (unsigned)v < 8u) {
                int f = (chunk * 32 + co_l) * 16 + (u >> 1) * 4 + (v >> 1);
                if (i0p[f] == ((u & 1) * 2 + (v & 1))) val = s1p[f];
            }
            pad[i] = val;
        }
        __syncthreads();
        const float* wbase = Wt + ci * 3200 + chunk * 800;   // 32*25 floats/chunk
        const float* pb = pad + y0 * 16 + x0;
        for (int co = 0; co < 32; co++) {
            float win[36];
            const float* bp = pb + co * 256;
#pragma unroll
            for (int r = 0; r < 6; r++) {
                const float2* rp = (const float2*)(bp + r * 16);  // even-aligned
                float2 v0 = rp[0], v1 = rp[1], v2 = rp[2];
                win[r * 6 + 0] = v0.x; win[r * 6 + 1] = v0.y;
                win[r * 6 + 2] = v1.x; win[r * 6 + 3] = v1.y;
                win[r * 6 + 4] = v2.x; win[r * 6 + 5] = v2.y;
            }
            const float* wr = wbase + co * 25;
#pragma unroll
            for (int kh = 0; kh < 5; kh++)
#pragma unroll
            for (int kw = 0; kw < 5; kw++) {
                float wv = wr[kh * 5 + kw];
                a00 = nacc(win[kh * 6 + kw],           wv, a00);
                a01 = nacc(win[kh * 6 + kw + 1],       wv, a01);
                a10 = nacc(win[(kh + 1) * 6 + kw],     wv, a10);
                a11 = nacc(win[(kh + 1) * 6 + kw + 1], wv, a11);
            }
        }
    }
    int pbase = b * S2SZ + ci * 144;
    float acc[4] = {a00, a01, a10, a11};
#pragma unroll
    for (int dy = 0; dy < 2; dy++)
#pragma unroll
    for (int dx = 0; dx < 2; dx++) {
        int o = pbase + (y0 + dy) * 12 + (x0 + dx);
        float s2o = s_old[O_S2 + o];
        s_new[O_S2 + o] = s2o + DT * (rho(__fadd_rn(p1[o], acc[dy * 2 + dx])) - s2o);
    }
}

extern "C" void kernel_launch(void* const* d_in, const int* in_sizes, int n_in,
                              void* d_out, int out_size, void* d_ws, size_t ws_size,
                              hipStream_t stream) {
    const float* data  = (const float*)d_in[0];
    const float* s0_in = (const float*)d_in[1];
    const float* s1_in = (const float*)d_in[2];
    const float* s2_in = (const float*)d_in[3];
    const float* Wfc   = (const float*)d_in[4];
    const float* bfc   = (const float*)d_in[5];
    const float* Wc0   = (const float*)d_in[6];
    const float* bc0   = (const float*)d_in[7];
    const float* Wc1   = (const float*)d_in[8];
    const float* bc1   = (const float*)d_in[9];
    float* out = (float*)d_out;

    float* wsf = (float*)d_ws;
    float* X   = wsf;                          // ping-pong partner of d_out
    float* p1  = X + STATE_TOTAL;              // NB*S2SZ
    float* Wt  = p1 + NB * S2SZ;               // 204800
    int*   i0  = (int*)(Wt + 204800);          // NB*S1SZ

    size_t needed = (size_t)(STATE_TOTAL + NB * S2SZ + 204800 + NB * S1SZ) * 4;
    if (ws_size < needed) { k_sentinel<<<1, 1, 0, stream>>>(out); return; }

    // state t=0 -> d_out; 10 steps out->X->out... end in out
    hipMemcpyAsync(out + O_S0, s0_in, NB * S0N * sizeof(float), hipMemcpyDeviceToDevice, stream);
    hipMemcpyAsync(out + O_S1, s1_in, NB * S1SZ * sizeof(float), hipMemcpyDeviceToDevice, stream);
    hipMemcpyAsync(out + O_S2, s2_in, NB * S2SZ * sizeof(float), hipMemcpyDeviceToDevice, stream);

    k_p1<<<NB * 64 * 144 / 256, 256, 0, stream>>>(data, Wc1, bc1, p1);
    k_wt<<<204800 / 256, 256, 0, stream>>>(Wc0, Wt);

    for (int t = 0; t < T_RUN; t++) {
        const float* src = (t & 1) ? X : out;
        float*       dst = (t & 1) ? out : X;
        k_fc   <<<40,     64,  0, stream>>>(src, Wfc, bfc, dst);
        k_conv0<<<NB * 8, 256, 0, stream>>>(src, Wc0, bc0, Wfc, dst, i0);
        k_tconv<<<NB * 9, 256, 0, stream>>>(src, Wt, p1, i0, dst);
    }
}